// Round 1
// baseline (537.747 us; speedup 1.0000x reference)
//
#include <hip/hip_runtime.h>
#include <stdint.h>

#define NN   8192
#define DIN  256
#define DOUT 32

typedef short bf16x8 __attribute__((ext_vector_type(8)));
typedef float f32x16 __attribute__((ext_vector_type(16)));

union BF8 { uint32_t u[4]; bf16x8 v; };

// Split fp32 pair into packed bf16 hi (truncated top 16 bits) and bf16 lo (residual).
// a ~= hi + lo with |error| ~ |a| * 2^-16.
__device__ __forceinline__ void split_pair(float a, float b, uint32_t& hp, uint32_t& lp) {
    uint32_t ua = __float_as_uint(a), ub = __float_as_uint(b);
    hp = (ua >> 16) | (ub & 0xffff0000u);
    float la = a - __uint_as_float(ua & 0xffff0000u);
    float lb = b - __uint_as_float(ub & 0xffff0000u);
    lp = (__float_as_uint(la) >> 16) | (__float_as_uint(lb) & 0xffff0000u);
}

// ---------------------------------------------------------------------------
// K1: support = X @ W  (fp32 accumulate), emitted as bf16 hi/lo MFMA B-fragments.
// B-frag layout for v_mfma_f32_32x32x16_bf16: lane l holds B[k=(l>>5)*8+j][n=l&31].
// Flat frag index: ks*512 + lane*8 + j   (ks = k/16).
// Block: 32 k-rows, 256 threads; thread owns (c, 4 consecutive j's of one half).
__global__ __launch_bounds__(256) void k1_support(
    const float* __restrict__ X, const float* __restrict__ W,
    unsigned short* __restrict__ hi_frag, unsigned short* __restrict__ lo_frag)
{
    __shared__ float Xs[32 * 256];   // 32 KB
    int t = threadIdx.x;
    int kbase = blockIdx.x * 32;

    const float4* Xg = (const float4*)(X + (size_t)kbase * DIN);
    float4* Xs4 = (float4*)Xs;
#pragma unroll
    for (int p = 0; p < 8; ++p) Xs4[p * 256 + t] = Xg[p * 256 + t];
    __syncthreads();

    int c = t & 31;
    int q = t >> 5;                 // 0..7
    int kb2  = q >> 2;              // 0..1  (which 16-k block inside the 32 rows)
    int half = (q >> 1) & 1;        // lane-half (k offset 0 or 8)
    int j4   = q & 1;               // which group of 4 j's
    int krow0 = kb2 * 16 + half * 8 + j4 * 4;

    float acc[4] = {0.f, 0.f, 0.f, 0.f};
    for (int d = 0; d < 256; ++d) {
        float w = W[d * 32 + c];    // L1-resident, lane-coalesced
#pragma unroll
        for (int jj = 0; jj < 4; ++jj)
            acc[jj] += Xs[(krow0 + jj) * 256 + d] * w;
    }

    uint32_t h01, l01, h23, l23;
    split_pair(acc[0], acc[1], h01, l01);
    split_pair(acc[2], acc[3], h23, l23);

    int ks = (kbase >> 4) + kb2;
    size_t elembase = (size_t)ks * 512 + (size_t)(half * 32 + c) * 8 + j4 * 4;
    *(uint2*)(hi_frag + elembase) = make_uint2(h01, h23);
    *(uint2*)(lo_frag + elembase) = make_uint2(l01, l23);
}

// ---------------------------------------------------------------------------
// K2: logits += adj @ support  via split-bf16 MFMA. No LDS, no barriers.
// Grid: (64 row-blocks of 128, 16 k-chunks of 512). Block = 4 independent waves,
// each owning a 32-row tile. A-frag: lane l = row (l&31), k = (l>>5)*8 + j, i.e.
// 8 consecutive fp32 (32B) per lane straight from row-major adj.
__global__ __launch_bounds__(256) void k2_logits(
    const float* __restrict__ adj,
    const unsigned short* __restrict__ hi_frag,
    const unsigned short* __restrict__ lo_frag,
    float* __restrict__ logits)
{
    int t = threadIdx.x;
    int lane = t & 63, wv = t >> 6;
    int row_tile = blockIdx.x * 128 + wv * 32;
    int r  = lane & 31;
    int hs = lane >> 5;

    const float* arow = adj + (size_t)(row_tile + r) * NN + blockIdx.y * 512 + hs * 8;
    const unsigned short* hp = hi_frag + (size_t)blockIdx.y * 32 * 512 + lane * 8;
    const unsigned short* lp = lo_frag + (size_t)blockIdx.y * 32 * 512 + lane * 8;

    f32x16 acc;
#pragma unroll
    for (int i = 0; i < 16; ++i) acc[i] = 0.f;

#pragma unroll 4
    for (int s = 0; s < 32; ++s) {           // 32 k-steps of 16 => k-chunk 512
        float4 a0 = *(const float4*)arow;
        float4 a1 = *(const float4*)(arow + 4);
        BF8 bh, bl, ah, al;
        bh.v = *(const bf16x8*)hp;
        bl.v = *(const bf16x8*)lp;
        split_pair(a0.x, a0.y, ah.u[0], al.u[0]);
        split_pair(a0.z, a0.w, ah.u[1], al.u[1]);
        split_pair(a1.x, a1.y, ah.u[2], al.u[2]);
        split_pair(a1.z, a1.w, ah.u[3], al.u[3]);
        acc = __builtin_amdgcn_mfma_f32_32x32x16_bf16(ah.v, bh.v, acc, 0, 0, 0);
        acc = __builtin_amdgcn_mfma_f32_32x32x16_bf16(ah.v, bl.v, acc, 0, 0, 0);
        acc = __builtin_amdgcn_mfma_f32_32x32x16_bf16(al.v, bh.v, acc, 0, 0, 0);
        arow += 16; hp += 512; lp += 512;
    }

    // D layout: col = lane&31, row = (reg&3) + 8*(reg>>2) + 4*(lane>>5)  [m74/m101]
#pragma unroll
    for (int reg = 0; reg < 16; ++reg) {
        int rt = (reg & 3) + 8 * (reg >> 2) + 4 * hs;
        atomicAdd(&logits[(size_t)(row_tile + rt) * 32 + r], acc[reg]);
    }
}

// ---------------------------------------------------------------------------
// K3: in-place softmax over the node axis (dim 0). One block per column.
// b is omitted: softmax over rows is invariant to a per-column constant shift.
__global__ __launch_bounds__(256) void k3_softmax(float* __restrict__ logits)
{
    int c = blockIdx.x, t = threadIdx.x;
    __shared__ float red[256];

    float x[32];
    float m = -3.4e38f;
#pragma unroll
    for (int p = 0; p < 32; ++p) {
        x[p] = logits[(size_t)(p * 256 + t) * 32 + c];
        m = fmaxf(m, x[p]);
    }
    red[t] = m; __syncthreads();
    for (int s = 128; s > 0; s >>= 1) {
        if (t < s) red[t] = fmaxf(red[t], red[t + s]);
        __syncthreads();
    }
    float M = red[0]; __syncthreads();

    float ssum = 0.f;
#pragma unroll
    for (int p = 0; p < 32; ++p) { x[p] = __expf(x[p] - M); ssum += x[p]; }
    red[t] = ssum; __syncthreads();
    for (int s = 128; s > 0; s >>= 1) {
        if (t < s) red[t] += red[t + s];
        __syncthreads();
    }
    float inv = 1.0f / red[0];
#pragma unroll
    for (int p = 0; p < 32; ++p)
        logits[(size_t)(p * 256 + t) * 32 + c] = x[p] * inv;
}

// ---------------------------------------------------------------------------
// K4: raw_emb[c][d] = sum_i assign[i][c] * X[i][d].  i-chunks of 32 per block,
// LDS-staged, atomic accumulate into zeroed d_out.
__global__ __launch_bounds__(256) void k4_pool(
    const float* __restrict__ X, const float* __restrict__ assign,
    float* __restrict__ out)
{
    __shared__ float Xs[8 * 256];   // 8 KB
    __shared__ float As[8 * 32];    // 1 KB
    int t = threadIdx.x;
    int c = t & 31, dg = t >> 5;    // dg in 0..7 -> 32-wide d slice
    int ibase = blockIdx.x * 32;

    float acc[32];
#pragma unroll
    for (int i = 0; i < 32; ++i) acc[i] = 0.f;

    for (int rnd = 0; rnd < 4; ++rnd) {
        __syncthreads();
        const float4* Xg = (const float4*)(X + (size_t)(ibase + rnd * 8) * DIN);
        float4* Xs4 = (float4*)Xs;
        Xs4[t]       = Xg[t];
        Xs4[256 + t] = Xg[256 + t];
        As[t] = assign[(size_t)(ibase + rnd * 8 + (t >> 5)) * 32 + (t & 31)];
        __syncthreads();
#pragma unroll
        for (int i2 = 0; i2 < 8; ++i2) {
            float a = As[i2 * 32 + c];
#pragma unroll
            for (int dd = 0; dd < 32; ++dd)
                acc[dd] += a * Xs[i2 * 256 + dg * 32 + dd];
        }
    }
#pragma unroll
    for (int dd = 0; dd < 32; ++dd)
        atomicAdd(&out[(size_t)c * 256 + dg * 32 + dd], acc[dd]);
}

// ---------------------------------------------------------------------------
extern "C" void kernel_launch(void* const* d_in, const int* in_sizes, int n_in,
                              void* d_out, int out_size, void* d_ws, size_t ws_size,
                              hipStream_t stream) {
    const float* X   = (const float*)d_in[0];   // [8192, 256]
    const float* adj = (const float*)d_in[1];   // [8192, 8192]
    const float* W   = (const float*)d_in[2];   // [256, 32]
    // d_in[3] = b: ignored — softmax over dim 0 is invariant to per-column shift.
    float* out = (float*)d_out;                 // [32, 256]

    // ws layout: hi_frag 512KB | lo_frag 512KB | logits 1MB  (2 MB total)
    unsigned short* hi_frag = (unsigned short*)d_ws;
    unsigned short* lo_frag = hi_frag + (size_t)NN * DOUT;
    float* logits = (float*)((char*)d_ws + 2u * NN * DOUT * sizeof(unsigned short));

    hipMemsetAsync(logits, 0, (size_t)NN * DOUT * sizeof(float), stream);
    hipMemsetAsync(d_out, 0, (size_t)DOUT * DIN * sizeof(float), stream);

    k1_support<<<NN / 32, 256, 0, stream>>>(X, W, hi_frag, lo_frag);
    k2_logits<<<dim3(NN / 128, 16), 256, 0, stream>>>(adj, hi_frag, lo_frag, logits);
    k3_softmax<<<DOUT, 256, 0, stream>>>(logits);
    k4_pool<<<NN / 32, 256, 0, stream>>>(X, logits, out);
}

// Round 2
// 439.287 us; speedup vs baseline: 1.2241x; 1.2241x over previous
//
#include <hip/hip_runtime.h>
#include <stdint.h>

#define NN   8192
#define DIN  256
#define DOUT 32

typedef short bf16x8 __attribute__((ext_vector_type(8)));
typedef float f32x16 __attribute__((ext_vector_type(16)));

union BF8 { uint32_t u[4]; bf16x8 v; };

// Split fp32 pair into packed bf16 hi (truncated top 16 bits) and bf16 lo (residual).
// a ~= hi + lo with |error| ~ |a| * 2^-16 after both terms.
__device__ __forceinline__ void split_pair(float a, float b, uint32_t& hp, uint32_t& lp) {
    uint32_t ua = __float_as_uint(a), ub = __float_as_uint(b);
    hp = (ua >> 16) | (ub & 0xffff0000u);
    float la = a - __uint_as_float(ua & 0xffff0000u);
    float lb = b - __uint_as_float(ub & 0xffff0000u);
    lp = (__float_as_uint(la) >> 16) | (__float_as_uint(lb) & 0xffff0000u);
}

// ---------------------------------------------------------------------------
// K1: support = X @ W (fp32 accumulate), emitted as bf16 hi/lo MFMA B-fragments.
// B-frag layout (v_mfma_f32_32x32x16_bf16): lane l holds B[k=(l>>5)*8+j][n=l&31].
__global__ __launch_bounds__(256) void k1_support(
    const float* __restrict__ X, const float* __restrict__ W,
    unsigned short* __restrict__ hi_frag, unsigned short* __restrict__ lo_frag)
{
    __shared__ float Xs[32 * 256];   // 32 KB
    int t = threadIdx.x;
    int kbase = blockIdx.x * 32;

    const float4* Xg = (const float4*)(X + (size_t)kbase * DIN);
    float4* Xs4 = (float4*)Xs;
#pragma unroll
    for (int p = 0; p < 8; ++p) Xs4[p * 256 + t] = Xg[p * 256 + t];
    __syncthreads();

    int c = t & 31;
    int q = t >> 5;
    int kb2  = q >> 2;
    int half = (q >> 1) & 1;
    int j4   = q & 1;
    int krow0 = kb2 * 16 + half * 8 + j4 * 4;

    float acc[4] = {0.f, 0.f, 0.f, 0.f};
    for (int d = 0; d < 256; ++d) {
        float w = W[d * 32 + c];
#pragma unroll
        for (int jj = 0; jj < 4; ++jj)
            acc[jj] += Xs[(krow0 + jj) * 256 + d] * w;
    }

    uint32_t h01, l01, h23, l23;
    split_pair(acc[0], acc[1], h01, l01);
    split_pair(acc[2], acc[3], h23, l23);

    int ks = (kbase >> 4) + kb2;
    size_t elembase = (size_t)ks * 512 + (size_t)(half * 32 + c) * 8 + j4 * 4;
    *(uint2*)(hi_frag + elembase) = make_uint2(h01, h23);
    *(uint2*)(lo_frag + elembase) = make_uint2(l01, l23);
}

// ---------------------------------------------------------------------------
// K2: partial logits via split-bf16 MFMA. No LDS, no barriers, NO atomics:
// each k-chunk (blockIdx.y) writes its own 1 MB partial buffer.
__global__ __launch_bounds__(256) void k2_logits(
    const float* __restrict__ adj,
    const unsigned short* __restrict__ hi_frag,
    const unsigned short* __restrict__ lo_frag,
    float* __restrict__ part)     // [16][NN*DOUT]
{
    int t = threadIdx.x;
    int lane = t & 63, wv = t >> 6;
    int row_tile = blockIdx.x * 128 + wv * 32;
    int r  = lane & 31;
    int hs = lane >> 5;

    const float* arow = adj + (size_t)(row_tile + r) * NN + blockIdx.y * 512 + hs * 8;
    const unsigned short* hp = hi_frag + (size_t)blockIdx.y * 32 * 512 + lane * 8;
    const unsigned short* lp = lo_frag + (size_t)blockIdx.y * 32 * 512 + lane * 8;

    f32x16 acc;
#pragma unroll
    for (int i = 0; i < 16; ++i) acc[i] = 0.f;

#pragma unroll 4
    for (int s = 0; s < 32; ++s) {
        float4 a0 = *(const float4*)arow;
        float4 a1 = *(const float4*)(arow + 4);
        BF8 bh, bl, ah, al;
        bh.v = *(const bf16x8*)hp;
        bl.v = *(const bf16x8*)lp;
        split_pair(a0.x, a0.y, ah.u[0], al.u[0]);
        split_pair(a0.z, a0.w, ah.u[1], al.u[1]);
        split_pair(a1.x, a1.y, ah.u[2], al.u[2]);
        split_pair(a1.z, a1.w, ah.u[3], al.u[3]);
        acc = __builtin_amdgcn_mfma_f32_32x32x16_bf16(ah.v, bh.v, acc, 0, 0, 0);
        acc = __builtin_amdgcn_mfma_f32_32x32x16_bf16(ah.v, bl.v, acc, 0, 0, 0);
        acc = __builtin_amdgcn_mfma_f32_32x32x16_bf16(al.v, bh.v, acc, 0, 0, 0);
        arow += 16; hp += 512; lp += 512;
    }

    float* pdst = part + (size_t)blockIdx.y * (NN * DOUT);
    // D layout: col = lane&31, row = (reg&3) + 8*(reg>>2) + 4*(lane>>5)
#pragma unroll
    for (int reg = 0; reg < 16; ++reg) {
        int rt = (reg & 3) + 8 * (reg >> 2) + 4 * hs;
        pdst[(size_t)(row_tile + rt) * 32 + r] = acc[reg];
    }
}

// ---------------------------------------------------------------------------
// K3a: coalesced sum of the 16 partials -> logits_sum; per-block column maxes.
// Block = 128 rows (4096 floats = 1024 float4). Element j of thread t's float4
// always lands in column (4t+j)&31 -> col-group g = t&7 is thread-invariant.
__global__ __launch_bounds__(256) void k3a_sum_max(
    const float* __restrict__ part, float* __restrict__ logits_sum,
    float* __restrict__ Mpart)
{
    __shared__ float red[256 * 4];
    int t = threadIdx.x;
    size_t base4 = (size_t)blockIdx.x * 1024;

    float mx[4] = {-3.4e38f, -3.4e38f, -3.4e38f, -3.4e38f};
#pragma unroll
    for (int k = 0; k < 4; ++k) {
        size_t f = base4 + k * 256 + t;
        float4 v = ((const float4*)part)[f];
#pragma unroll
        for (int p = 1; p < 16; ++p) {
            float4 u = ((const float4*)(part + (size_t)p * NN * DOUT))[f];
            v.x += u.x; v.y += u.y; v.z += u.z; v.w += u.w;
        }
        ((float4*)logits_sum)[f] = v;
        mx[0] = fmaxf(mx[0], v.x); mx[1] = fmaxf(mx[1], v.y);
        mx[2] = fmaxf(mx[2], v.z); mx[3] = fmaxf(mx[3], v.w);
    }
#pragma unroll
    for (int j = 0; j < 4; ++j) red[t * 4 + j] = mx[j];
    __syncthreads();
    for (int s = 128; s >= 8; s >>= 1) {
        if (t < s)
#pragma unroll
            for (int j = 0; j < 4; ++j)
                red[t * 4 + j] = fmaxf(red[t * 4 + j], red[(t + s) * 4 + j]);
        __syncthreads();
    }
    if (t < 8)
#pragma unroll
        for (int j = 0; j < 4; ++j)
            Mpart[blockIdx.x * 32 + t * 4 + j] = red[t * 4 + j];
}

// ---------------------------------------------------------------------------
// K3b: fold column maxes (redundantly per block), e = exp(x - M[col]) -> e_buf,
// per-block column sums -> Spart.
__global__ __launch_bounds__(256) void k3b_exp_sum(
    const float* __restrict__ logits_sum, const float* __restrict__ Mpart,
    float* __restrict__ e_buf, float* __restrict__ Spart)
{
    __shared__ float Ms[32];
    __shared__ float red[256 * 4];
    int t = threadIdx.x;

    if (t < 32) {
        float m = -3.4e38f;
        for (int g = 0; g < 64; ++g) m = fmaxf(m, Mpart[g * 32 + t]);
        Ms[t] = m;
    }
    __syncthreads();

    int g = t & 7;
    float m0 = Ms[4 * g], m1 = Ms[4 * g + 1], m2 = Ms[4 * g + 2], m3 = Ms[4 * g + 3];
    size_t base4 = (size_t)blockIdx.x * 1024;
    float sm[4] = {0.f, 0.f, 0.f, 0.f};
#pragma unroll
    for (int k = 0; k < 4; ++k) {
        size_t f = base4 + k * 256 + t;
        float4 v = ((const float4*)logits_sum)[f];
        v.x = __expf(v.x - m0); v.y = __expf(v.y - m1);
        v.z = __expf(v.z - m2); v.w = __expf(v.w - m3);
        ((float4*)e_buf)[f] = v;
        sm[0] += v.x; sm[1] += v.y; sm[2] += v.z; sm[3] += v.w;
    }
#pragma unroll
    for (int j = 0; j < 4; ++j) red[t * 4 + j] = sm[j];
    __syncthreads();
    for (int s = 128; s >= 8; s >>= 1) {
        if (t < s)
#pragma unroll
            for (int j = 0; j < 4; ++j)
                red[t * 4 + j] += red[(t + s) * 4 + j];
        __syncthreads();
    }
    if (t < 8)
#pragma unroll
        for (int j = 0; j < 4; ++j)
            Spart[blockIdx.x * 32 + t * 4 + j] = red[t * 4 + j];
}

// ---------------------------------------------------------------------------
// K4: per-block partial pooling. 128 blocks x 64 rows. assign = e * invS folded
// on load (invS reduced redundantly per block from Spart). No atomics.
__global__ __launch_bounds__(256) void k4_pool(
    const float* __restrict__ X, const float* __restrict__ e_buf,
    const float* __restrict__ Spart, float* __restrict__ p4)
{
    __shared__ float Xs[8 * 256];   // 8 KB
    __shared__ float As[8 * 32];    // 1 KB
    __shared__ float invS[32];
    int t = threadIdx.x;
    int c = t & 31, dg = t >> 5;
    int ibase = blockIdx.x * 64;

    if (t < 32) {
        float s = 0.f;
        for (int g = 0; g < 64; ++g) s += Spart[g * 32 + t];
        invS[t] = 1.0f / s;
    }

    float acc[32];
#pragma unroll
    for (int i = 0; i < 32; ++i) acc[i] = 0.f;

    for (int rnd = 0; rnd < 8; ++rnd) {
        __syncthreads();
        const float4* Xg = (const float4*)(X + (size_t)(ibase + rnd * 8) * DIN);
        float4* Xs4 = (float4*)Xs;
        Xs4[t]       = Xg[t];
        Xs4[256 + t] = Xg[256 + t];
        As[t] = e_buf[(size_t)(ibase + rnd * 8 + (t >> 5)) * 32 + (t & 31)] * invS[t & 31];
        __syncthreads();
#pragma unroll
        for (int i2 = 0; i2 < 8; ++i2) {
            float a = As[i2 * 32 + c];
#pragma unroll
            for (int dd = 0; dd < 32; ++dd)
                acc[dd] += a * Xs[i2 * 256 + dg * 32 + dd];
        }
    }
    float* dst = p4 + (size_t)blockIdx.x * (DOUT * DIN) + (size_t)c * 256 + dg * 32;
#pragma unroll
    for (int v = 0; v < 8; ++v)
        ((float4*)dst)[v] = make_float4(acc[v * 4], acc[v * 4 + 1], acc[v * 4 + 2], acc[v * 4 + 3]);
}

// ---------------------------------------------------------------------------
// K5: reduce 128 block-partials -> out. Fully coalesced.
__global__ __launch_bounds__(256) void k5_reduce(
    const float* __restrict__ p4, float* __restrict__ out)
{
    int j = blockIdx.x * 256 + threadIdx.x;
    float a = 0.f;
    for (int g = 0; g < 128; ++g) a += p4[(size_t)g * (DOUT * DIN) + j];
    out[j] = a;
}

// ---------------------------------------------------------------------------
extern "C" void kernel_launch(void* const* d_in, const int* in_sizes, int n_in,
                              void* d_out, int out_size, void* d_ws, size_t ws_size,
                              hipStream_t stream) {
    const float* X   = (const float*)d_in[0];   // [8192, 256]
    const float* adj = (const float*)d_in[1];   // [8192, 8192]
    const float* W   = (const float*)d_in[2];   // [256, 32]
    // d_in[3] = b: ignored — softmax over dim 0 is invariant to per-column shift.
    float* out = (float*)d_out;                 // [32, 256]

    char* w = (char*)d_ws;
    unsigned short* hi_frag = (unsigned short*)w;                       // 512 KB
    unsigned short* lo_frag = (unsigned short*)(w + 512 * 1024);        // 512 KB
    float* part       = (float*)(w + 1 * 1024 * 1024);                  // 16 MB
    float* logits_sum = (float*)(w + 17 * 1024 * 1024);                 // 1 MB
    float* e_buf      = (float*)(w + 18 * 1024 * 1024);                 // 1 MB
    float* Mpart      = (float*)(w + 19 * 1024 * 1024);                 // 8 KB
    float* Spart      = (float*)(w + 19 * 1024 * 1024 + 8192);          // 8 KB
    float* p4         = (float*)(w + 19 * 1024 * 1024 + 16384);         // 4 MB

    k1_support<<<NN / 32, 256, 0, stream>>>(X, W, hi_frag, lo_frag);
    k2_logits<<<dim3(NN / 128, 16), 256, 0, stream>>>(adj, hi_frag, lo_frag, part);
    k3a_sum_max<<<64, 256, 0, stream>>>(part, logits_sum, Mpart);
    k3b_exp_sum<<<64, 256, 0, stream>>>(logits_sum, Mpart, e_buf, Spart);
    k4_pool<<<128, 256, 0, stream>>>(X, e_buf, Spart, p4);
    k5_reduce<<<DOUT * DIN / 256, 256, 0, stream>>>(p4, out);
}